// Round 10
// baseline (187.121 us; speedup 1.0000x reference)
//
#include <hip/hip_runtime.h>
#include <hip/hip_bf16.h>
#include <stdint.h>

typedef short short8 __attribute__((ext_vector_type(8)));
typedef float f32x4 __attribute__((ext_vector_type(4)));

// Problem constants
constexpr int SEQ   = 2048;   // T
constexpr int DM    = 1024;   // model dim
constexpr int NHEAD = 16;
constexpr int HD    = 64;     // head dim
constexpr int LDQ   = 1152;   // QKV row stride: 1024 Q | 64 K | 64 V
constexpr int BATCH = 2;

__device__ __forceinline__ unsigned short f2bf(float f) {
    union { float f; uint32_t u; } v; v.f = f;
    uint32_t u = v.u;
    uint32_t r = (u + 0x7fffu + ((u >> 16) & 1u)) >> 16;
    return (unsigned short)r;
}

// async global->LDS, 16B per lane. LDS dest = wave-uniform base + lane*16.
typedef __attribute__((address_space(1))) const void gvoid_t;
typedef __attribute__((address_space(3))) void lvoid_t;
__device__ __forceinline__ void gload16(const void* g, void* l) {
    __builtin_amdgcn_global_load_lds((gvoid_t*)g, (lvoid_t*)l, 16, 0, 0);
}

// ---------------- cast x (fp32 -> bf16), vectorized ----------------
__global__ __launch_bounds__(256) void cast_x_kernel(
        const float* __restrict__ x, unsigned short* __restrict__ xb, int n) {
    int i = (blockIdx.x * 256 + threadIdx.x) * 4;
    if (i >= n) return;
    const float4 v = *(const float4*)(x + i);
    ushort4 o;
    o.x = f2bf(v.x); o.y = f2bf(v.y); o.z = f2bf(v.z); o.w = f2bf(v.w);
    *(ushort4*)(xb + i) = o;
}

// ---- fused weight prep: cast+transpose Wq,Wk,Wv,Wo in one launch ----
__global__ __launch_bounds__(256) void prep_w_kernel(
        const float* __restrict__ Wq, const float* __restrict__ Wk,
        const float* __restrict__ Wv, const float* __restrict__ Wo,
        unsigned short* __restrict__ wtq, unsigned short* __restrict__ wot) {
    __shared__ unsigned short tile[32][33];
    int z = blockIdx.z;
    const float* W; unsigned short* Wt; int C;
    if (z == 0)      { W = Wq; Wt = wtq;                              C = DM; }
    else if (z == 1) { W = Wk; Wt = wtq + (size_t)DM * DM;            C = HD; }
    else if (z == 2) { W = Wv; Wt = wtq + (size_t)(DM + HD) * DM;     C = HD; }
    else             { W = Wo; Wt = wot;                              C = DM; }
    int c0 = blockIdx.x * 32, r0 = blockIdx.y * 32;
    if (c0 >= C) return;
    int tx = threadIdx.x & 31, ty = threadIdx.x >> 5;  // ty 0..7
    for (int i = ty; i < 32; i += 8)
        tile[i][tx] = f2bf(W[(size_t)(r0 + i) * C + (c0 + tx)]);
    __syncthreads();
    for (int i = ty; i < 32; i += 8)
        Wt[(size_t)(c0 + i) * DM + (r0 + tx)] = tile[tx][i];
}

// ------------- GEMM: C[M,N] = A[M,K](bf16) @ Bt[N,K]^T(bf16) -------------
// 64x64 tile (qkv: 1152 blocks = 4.5/CU; out: 1024 = 4/CU). BK=64 staged
// via global_load_lds with (row&7) xor chunk swizzle (conflict-free b128
// fragment reads). Double-buffered. 4 waves in 2x2, each 32x32 out.
__global__ __launch_bounds__(256) void gemm_bt_kernel(
        const unsigned short* __restrict__ A,
        const unsigned short* __restrict__ Bt,
        void* __restrict__ Cout,
        unsigned short* __restrict__ VtOut,
        int M, int N, int K, int out_bf16) {
    __shared__ unsigned short ldsA[2][64 * 64];
    __shared__ unsigned short ldsB[2][64 * 64];
    int lane = threadIdx.x & 63, wave = threadIdx.x >> 6;
    int ln = lane & 15, quad = lane >> 4;
    int wm = wave >> 1, wn = wave & 1;
    int m0 = blockIdx.y * 64, n0 = blockIdx.x * 64;

    int t = threadIdx.x;
    int trow = t >> 3, tcb = t & 7;
    int gcb = tcb ^ (trow & 7);
    const unsigned short* gA = A + (size_t)(m0 + trow) * K + gcb * 8;
    const unsigned short* gA2 = gA + (size_t)32 * K;
    const unsigned short* gB = Bt + (size_t)(n0 + trow) * K + gcb * 8;
    const unsigned short* gB2 = gB + (size_t)32 * K;
    int dst = t * 8;   // shorts; rr=1 adds 2048

    auto stage = [&](int k0, int buf) {
        gload16(gA + k0, &ldsA[buf][dst]);
        gload16(gA2 + k0, &ldsA[buf][dst + 2048]);
        gload16(gB + k0, &ldsB[buf][dst]);
        gload16(gB2 + k0, &ldsB[buf][dst + 2048]);
    };

    f32x4 acc[2][2];
    for (int i = 0; i < 2; ++i)
        for (int jj = 0; jj < 2; ++jj) acc[i][jj] = f32x4{0, 0, 0, 0};

    stage(0, 0);
    int niter = K >> 6;
    for (int it = 0; it < niter; ++it) {
        __syncthreads();
        if (it + 1 < niter) stage((it + 1) << 6, (it + 1) & 1);
        const unsigned short* La = ldsA[it & 1];
        const unsigned short* Lb = ldsB[it & 1];
        short8 aF[2][2], bF[2][2];
#pragma unroll
        for (int hh = 0; hh < 2; ++hh) {
            int kc = hh * 4 + quad;
#pragma unroll
            for (int mt = 0; mt < 2; ++mt)
                aF[hh][mt] = *(const short8*)&La[(wm * 32 + mt * 16 + ln) * 64 +
                                                ((kc ^ (ln & 7)) * 8)];
#pragma unroll
            for (int nt = 0; nt < 2; ++nt)
                bF[hh][nt] = *(const short8*)&Lb[(wn * 32 + nt * 16 + ln) * 64 +
                                                ((kc ^ (ln & 7)) * 8)];
        }
#pragma unroll
        for (int hh = 0; hh < 2; ++hh)
#pragma unroll
            for (int mt = 0; mt < 2; ++mt)
#pragma unroll
                for (int nt = 0; nt < 2; ++nt)
                    acc[mt][nt] = __builtin_amdgcn_mfma_f32_16x16x32_bf16(
                        aF[hh][mt], bF[hh][nt], acc[mt][nt], 0, 0, 0);
    }

    if (out_bf16) {
        unsigned short* C = (unsigned short*)Cout;
#pragma unroll
        for (int mt = 0; mt < 2; ++mt)
            for (int nt = 0; nt < 2; ++nt)
                for (int r = 0; r < 4; ++r) {
                    int row = m0 + wm * 32 + mt * 16 + quad * 4 + r;
                    int col = n0 + wn * 32 + nt * 16 + ln;
                    C[(size_t)row * N + col] = f2bf(acc[mt][nt][r]);
                }
        if (VtOut != nullptr && n0 == DM + HD) {   // V block: also write transposed
#pragma unroll
            for (int mt = 0; mt < 2; ++mt)
                for (int nt = 0; nt < 2; ++nt)
                    for (int r = 0; r < 4; ++r) {
                        int row = m0 + wm * 32 + mt * 16 + quad * 4 + r;
                        int d = wn * 32 + nt * 16 + ln;          // 0..63
                        int bb = row >> 11, s = row & 2047;
                        VtOut[((size_t)bb * HD + d) * SEQ + s] = f2bf(acc[mt][nt][r]);
                    }
        }
    } else {
        float* C = (float*)Cout;
#pragma unroll
        for (int mt = 0; mt < 2; ++mt)
            for (int nt = 0; nt < 2; ++nt)
                for (int r = 0; r < 4; ++r) {
                    int row = m0 + wm * 32 + mt * 16 + quad * 4 + r;
                    int col = n0 + wn * 32 + nt * 16 + ln;
                    C[(size_t)row * N + col] = acc[mt][nt][r];
                }
    }
}

// ---------------- flash attention (multi-query, causal) ----------------
// 32 QUERIES PER WAVE (two 16q sub-tiles), head-grouped blocks:
//   MQA K/V depend only on batch, so a block's 4 waves = 4 HEADS x the SAME
//   32q tile j -> identical key range, shared K/V staging, uniform work.
//   K-frags (8 b128) read ONCE serve both q sub-tiles' QK; V-frags (8 b128)
//   read once into regs serve both PV passes. pbuf (16x64, per-wave, xor-
//   swizzled, conflict-free per R7) reused sequentially: qi0's P goes
//   through pbuf first; qi1's P is deferred in 16 VGPRs, then written.
// K(64x64)+Vt(64x64) double-buffered via global_load_lds, (row&7) xor
// swizzle. LDS 40 KB. Grid 512 (2/CU), heavy-first by j.
// Constant-max streaming softmax; P stored by truncation.
__global__ __launch_bounds__(256) void attn_kernel(
        const unsigned short* __restrict__ QKV,
        const unsigned short* __restrict__ Vt,
        unsigned short* __restrict__ Y) {
    __shared__ unsigned short ldsK[2][64 * 64];
    __shared__ unsigned short ldsV[2][64 * 64];
    __shared__ unsigned short pbuf[4][16 * 64];   // per-wave, swizzled

    int lane = threadIdx.x & 63, wave = threadIdx.x >> 6;
    int ln = lane & 15, quad = lane >> 4;
    int bid = blockIdx.x;
    int j = 63 - (bid >> 3);              // heavy-first: big key ranges first
    int sub = bid & 7;
    int hg = sub >> 1, b = sub & 1;
    int h = hg * 4 + wave;                // this wave's head
    int q0 = j * 32;                      // 32 queries: q0 .. q0+31
    const size_t baseRow = (size_t)b * SEQ;
    const unsigned short* Vb = Vt + (size_t)b * HD * SEQ;

    int t = threadIdx.x;
    int trow = t >> 3, tcb = t & 7;
    int cbg = tcb ^ (trow & 7);
    const unsigned short* gK = QKV + (baseRow + trow) * LDQ + DM + cbg * 8;
    const unsigned short* gV = Vb + (size_t)trow * SEQ + cbg * 8;
    int dstoff = trow * 64 + tcb * 8;

    auto stageKV = [&](int s0n, int buf) {
#pragma unroll
        for (int rr = 0; rr < 2; ++rr) {
            gload16(gK + (size_t)(s0n + 32 * rr) * LDQ, &ldsK[buf][dstoff + rr * 2048]);
            gload16(gV + (size_t)32 * rr * SEQ + s0n,   &ldsV[buf][dstoff + rr * 2048]);
        }
    };

    // Q fragments (A-layout) for both sub-tiles
    short8 aQ[2][2];
#pragma unroll
    for (int qi = 0; qi < 2; ++qi) {
        const unsigned short* qp = QKV + (baseRow + q0 + qi * 16 + ln) * LDQ + h * HD + quad * 8;
        aQ[qi][0] = *(const short8*)(qp);
        aQ[qi][1] = *(const short8*)(qp + 32);
    }

    float lsum[2][4];
    f32x4 o[2][4];
#pragma unroll
    for (int qi = 0; qi < 2; ++qi) {
        for (int r = 0; r < 4; ++r) lsum[qi][r] = 0.f;
        for (int nt = 0; nt < 4; ++nt) o[qi][nt] = f32x4{0, 0, 0, 0};
    }

    const float c_exp = 0.1803368802f;    // 0.125 * log2(e)
    unsigned short* pb = &pbuf[wave][0];
    // nsteps covers keys up to q0+31
    const int nsteps = (32 * j + 95) >> 6;

    auto computeStep = [&](int s0, int buf, bool partial) {
        const unsigned short* Kb = ldsK[buf];
        const unsigned short* Vf = ldsV[buf];
        float p1[4][4];                   // deferred qi=1 P values
        // Phase A: QK for both sub-tiles; qi0 -> pbuf, qi1 -> regs
#pragma unroll
        for (int c = 0; c < 4; ++c) {
            int kbase = s0 + c * 16;
            bool e0 = partial && (kbase > q0 + 15);   // qi0 sub-tile empty
            bool e1 = partial && (kbase > q0 + 31);   // qi1 sub-tile empty
            short8 kf0 = {}, kf1 = {};
            if (!e1) {
                kf0 = *(const short8*)&Kb[(c * 16 + ln) * 64 + ((quad ^ (ln & 7)) * 8)];
                kf1 = *(const short8*)&Kb[(c * 16 + ln) * 64 + (((4 + quad) ^ (ln & 7)) * 8)];
            }
            if (e0) {
#pragma unroll
                for (int r = 0; r < 4; ++r) {
                    int row = quad * 4 + r;
                    pb[row * 64 + (((c * 2 + (ln >> 3)) ^ (row & 7)) * 8) + (ln & 7)] = 0;
                }
            } else {
                f32x4 s = {0, 0, 0, 0};
                s = __builtin_amdgcn_mfma_f32_16x16x32_bf16(aQ[0][0], kf0, s, 0, 0, 0);
                s = __builtin_amdgcn_mfma_f32_16x16x32_bf16(aQ[0][1], kf1, s, 0, 0, 0);
                bool diag = partial && (kbase + 15 > q0);
#pragma unroll
                for (int r = 0; r < 4; ++r) {
                    float e = __builtin_exp2f(s[r] * c_exp);
                    if (diag && (kbase + ln > q0 + quad * 4 + r)) e = 0.f;
                    lsum[0][r] += e;
                    int row = quad * 4 + r;
                    pb[row * 64 + (((c * 2 + (ln >> 3)) ^ (row & 7)) * 8) + (ln & 7)] =
                        (unsigned short)(__float_as_uint(e) >> 16);
                }
            }
            if (e1) {
#pragma unroll
                for (int r = 0; r < 4; ++r) p1[c][r] = 0.f;
            } else {
                f32x4 s = {0, 0, 0, 0};
                s = __builtin_amdgcn_mfma_f32_16x16x32_bf16(aQ[1][0], kf0, s, 0, 0, 0);
                s = __builtin_amdgcn_mfma_f32_16x16x32_bf16(aQ[1][1], kf1, s, 0, 0, 0);
                bool diag = partial && (kbase + 15 > q0 + 16);
#pragma unroll
                for (int r = 0; r < 4; ++r) {
                    float e = __builtin_exp2f(s[r] * c_exp);
                    if (diag && (kbase + ln > q0 + 16 + quad * 4 + r)) e = 0.f;
                    lsum[1][r] += e;
                    p1[c][r] = e;
                }
            }
        }
        // Phase B: PV for qi0; V fragments kept in regs for reuse
        short8 vr[4][2];
#pragma unroll
        for (int nt = 0; nt < 4; ++nt) {
            vr[nt][0] = *(const short8*)&Vf[(nt * 16 + ln) * 64 + ((quad ^ (ln & 7)) * 8)];
            vr[nt][1] = *(const short8*)&Vf[(nt * 16 + ln) * 64 + (((4 + quad) ^ (ln & 7)) * 8)];
        }
        {
            short8 aP0 = *(const short8*)&pb[ln * 64 + ((quad ^ (ln & 7)) * 8)];
            short8 aP1 = *(const short8*)&pb[ln * 64 + (((4 + quad) ^ (ln & 7)) * 8)];
#pragma unroll
            for (int nt = 0; nt < 4; ++nt) {
                o[0][nt] = __builtin_amdgcn_mfma_f32_16x16x32_bf16(aP0, vr[nt][0], o[0][nt], 0, 0, 0);
                o[0][nt] = __builtin_amdgcn_mfma_f32_16x16x32_bf16(aP1, vr[nt][1], o[0][nt], 0, 0, 0);
            }
        }
        // Phase C: write deferred qi1 P, PV for qi1 (reuses vr)
#pragma unroll
        for (int c = 0; c < 4; ++c)
            for (int r = 0; r < 4; ++r) {
                int row = quad * 4 + r;
                pb[row * 64 + (((c * 2 + (ln >> 3)) ^ (row & 7)) * 8) + (ln & 7)] =
                    (unsigned short)(__float_as_uint(p1[c][r]) >> 16);
            }
        {
            short8 aP0 = *(const short8*)&pb[ln * 64 + ((quad ^ (ln & 7)) * 8)];
            short8 aP1 = *(const short8*)&pb[ln * 64 + (((4 + quad) ^ (ln & 7)) * 8)];
#pragma unroll
            for (int nt = 0; nt < 4; ++nt) {
                o[1][nt] = __builtin_amdgcn_mfma_f32_16x16x32_bf16(aP0, vr[nt][0], o[1][nt], 0, 0, 0);
                o[1][nt] = __builtin_amdgcn_mfma_f32_16x16x32_bf16(aP1, vr[nt][1], o[1][nt], 0, 0, 0);
            }
        }
    };

    stageKV(0, 0);
    for (int it = 0; it < nsteps - 1; ++it) {      // full steps, mask-free
        __syncthreads();
        stageKV((it + 1) * 64, (it + 1) & 1);
        computeStep(it * 64, it & 1, false);
    }
    __syncthreads();
    computeStep((nsteps - 1) * 64, (nsteps - 1) & 1, true);   // partial step

    // epilogue: reduce l across the 16 lanes of each quad, then Y = O / l
#pragma unroll
    for (int qi = 0; qi < 2; ++qi) {
        for (int off = 1; off < 16; off <<= 1)
#pragma unroll
            for (int r = 0; r < 4; ++r) lsum[qi][r] += __shfl_xor(lsum[qi][r], off);
#pragma unroll
        for (int r = 0; r < 4; ++r) {
            float inv = 1.0f / lsum[qi][r];
            int t_idx = q0 + qi * 16 + quad * 4 + r;
            unsigned short* yp = Y + (baseRow + t_idx) * DM + h * HD + ln;
            for (int nt = 0; nt < 4; ++nt)
                yp[nt * 16] = f2bf(o[qi][nt][r] * inv);
        }
    }
}

extern "C" void kernel_launch(void* const* d_in, const int* in_sizes, int n_in,
                              void* d_out, int out_size, void* d_ws, size_t ws_size,
                              hipStream_t stream) {
    const float* x  = (const float*)d_in[0];
    const float* Wq = (const float*)d_in[1];
    const float* Wk = (const float*)d_in[2];
    const float* Wv = (const float*)d_in[3];
    const float* Wo = (const float*)d_in[4];
    float* out = (float*)d_out;

    char* ws = (char*)d_ws;
    // workspace (22.8 MB): slot0 is xb until qkv-gemm completes, then y.
    unsigned short* xb  = (unsigned short*)(ws);                // 4096x1024 bf16 (8 MB)
    unsigned short* y   = (unsigned short*)(ws);                // alias: attn out
    unsigned short* wtq = (unsigned short*)(ws + 8388608);      // 1152x1024 bf16
    unsigned short* wot = (unsigned short*)(ws + 10747904);     // 1024x1024 bf16
    unsigned short* qkv = (unsigned short*)(ws + 12845056);     // 4096x1152 bf16
    unsigned short* Vt  = (unsigned short*)(ws + 22282240);     // 2x64x2048 bf16 (0.5 MB)

    const int BT = BATCH * SEQ;  // 4096 rows

    hipLaunchKernelGGL(cast_x_kernel, dim3(BT * DM / 4 / 256), dim3(256), 0, stream,
                       x, xb, BT * DM);
    hipLaunchKernelGGL(prep_w_kernel, dim3(DM / 32, DM / 32, 4), dim3(256), 0, stream,
                       Wq, Wk, Wv, Wo, wtq, wot);

    // QKV = x @ [Wq|Wk|Wv] -> bf16; V block also written transposed to Vt
    hipLaunchKernelGGL(gemm_bt_kernel, dim3(LDQ / 64, BT / 64), dim3(256), 0, stream,
                       xb, wtq, (void*)qkv, Vt, BT, LDQ, DM, 1);

    // flash attention (32q/wave, head-grouped) -> y bf16 (overwrites xb)
    hipLaunchKernelGGL(attn_kernel, dim3(512), dim3(256), 0, stream,
                       qkv, Vt, y);

    // out = y @ Wo -> fp32
    hipLaunchKernelGGL(gemm_bt_kernel, dim3(DM / 64, BT / 64), dim3(256), 0, stream,
                       y, wot, (void*)out, nullptr, BT, DM, DM, 0);
}

// Round 11
// 165.152 us; speedup vs baseline: 1.1330x; 1.1330x over previous
//
#include <hip/hip_runtime.h>
#include <hip/hip_bf16.h>
#include <stdint.h>

typedef short short8 __attribute__((ext_vector_type(8)));
typedef float f32x4 __attribute__((ext_vector_type(4)));

// Problem constants
constexpr int SEQ   = 2048;   // T
constexpr int DM    = 1024;   // model dim
constexpr int NHEAD = 16;
constexpr int HD    = 64;     // head dim
constexpr int LDQ   = 1152;   // QKV row stride: 1024 Q | 64 K | 64 V
constexpr int BATCH = 2;

__device__ __forceinline__ unsigned short f2bf(float f) {
    union { float f; uint32_t u; } v; v.f = f;
    uint32_t u = v.u;
    uint32_t r = (u + 0x7fffu + ((u >> 16) & 1u)) >> 16;
    return (unsigned short)r;
}

// async global->LDS, 16B per lane. LDS dest = wave-uniform base + lane*16.
typedef __attribute__((address_space(1))) const void gvoid_t;
typedef __attribute__((address_space(3))) void lvoid_t;
__device__ __forceinline__ void gload16(const void* g, void* l) {
    __builtin_amdgcn_global_load_lds((gvoid_t*)g, (lvoid_t*)l, 16, 0, 0);
}

// ---------------- cast x (fp32 -> bf16), vectorized ----------------
__global__ __launch_bounds__(256) void cast_x_kernel(
        const float* __restrict__ x, unsigned short* __restrict__ xb, int n) {
    int i = (blockIdx.x * 256 + threadIdx.x) * 4;
    if (i >= n) return;
    const float4 v = *(const float4*)(x + i);
    ushort4 o;
    o.x = f2bf(v.x); o.y = f2bf(v.y); o.z = f2bf(v.z); o.w = f2bf(v.w);
    *(ushort4*)(xb + i) = o;
}

// ---- fused weight prep: cast+transpose Wq,Wk,Wv,Wo in one launch ----
__global__ __launch_bounds__(256) void prep_w_kernel(
        const float* __restrict__ Wq, const float* __restrict__ Wk,
        const float* __restrict__ Wv, const float* __restrict__ Wo,
        unsigned short* __restrict__ wtq, unsigned short* __restrict__ wot) {
    __shared__ unsigned short tile[32][33];
    int z = blockIdx.z;
    const float* W; unsigned short* Wt; int C;
    if (z == 0)      { W = Wq; Wt = wtq;                              C = DM; }
    else if (z == 1) { W = Wk; Wt = wtq + (size_t)DM * DM;            C = HD; }
    else if (z == 2) { W = Wv; Wt = wtq + (size_t)(DM + HD) * DM;     C = HD; }
    else             { W = Wo; Wt = wot;                              C = DM; }
    int c0 = blockIdx.x * 32, r0 = blockIdx.y * 32;
    if (c0 >= C) return;
    int tx = threadIdx.x & 31, ty = threadIdx.x >> 5;  // ty 0..7
    for (int i = ty; i < 32; i += 8)
        tile[i][tx] = f2bf(W[(size_t)(r0 + i) * C + (c0 + tx)]);
    __syncthreads();
    for (int i = ty; i < 32; i += 8)
        Wt[(size_t)(c0 + i) * DM + (r0 + tx)] = tile[tx][i];
}

// ------------- GEMM: C[M,N] = A[M,K](bf16) @ Bt[N,K]^T(bf16) -------------
// 64x64 tile, BK=64, global_load_lds staging with (row&7) xor chunk swizzle,
// double-buffered. 1D grid with XCD-AWARE remap: dispatch assigns blockIdx
// round-robin to the 8 XCDs, so we map block g -> (row, col) such that all
// `ncols` column-blocks of a row-strip land on ONE XCD (g&7). The shared
// A row-tile is then fetched into a single per-XCD L2 and reused ncols
// times from L2 instead of ncols times from L3/HBM (per-XCD L2s are not
// coherent/shared). rows_per_xcd = grid/(8*ncols) must be integral.
__global__ __launch_bounds__(256) void gemm_bt_kernel(
        const unsigned short* __restrict__ A,
        const unsigned short* __restrict__ Bt,
        void* __restrict__ Cout,
        unsigned short* __restrict__ VtOut,
        int M, int N, int K, int out_bf16, int ncols) {
    __shared__ unsigned short ldsA[2][64 * 64];
    __shared__ unsigned short ldsB[2][64 * 64];
    int lane = threadIdx.x & 63, wave = threadIdx.x >> 6;
    int ln = lane & 15, quad = lane >> 4;
    int wm = wave >> 1, wn = wave & 1;

    // XCD-aware block remap
    int g = blockIdx.x;
    int xcd = g & 7, idx = g >> 3;
    int rows_per_xcd = (int)(gridDim.x >> 3) / ncols;
    int row = xcd * rows_per_xcd + idx / ncols;
    int col = idx % ncols;
    int m0 = row * 64, n0 = col * 64;

    int t = threadIdx.x;
    int trow = t >> 3, tcb = t & 7;
    int gcb = tcb ^ (trow & 7);
    const unsigned short* gA = A + (size_t)(m0 + trow) * K + gcb * 8;
    const unsigned short* gA2 = gA + (size_t)32 * K;
    const unsigned short* gB = Bt + (size_t)(n0 + trow) * K + gcb * 8;
    const unsigned short* gB2 = gB + (size_t)32 * K;
    int dst = t * 8;   // shorts; rr=1 adds 2048

    auto stage = [&](int k0, int buf) {
        gload16(gA + k0, &ldsA[buf][dst]);
        gload16(gA2 + k0, &ldsA[buf][dst + 2048]);
        gload16(gB + k0, &ldsB[buf][dst]);
        gload16(gB2 + k0, &ldsB[buf][dst + 2048]);
    };

    f32x4 acc[2][2];
    for (int i = 0; i < 2; ++i)
        for (int jj = 0; jj < 2; ++jj) acc[i][jj] = f32x4{0, 0, 0, 0};

    stage(0, 0);
    int niter = K >> 6;
    for (int it = 0; it < niter; ++it) {
        __syncthreads();
        if (it + 1 < niter) stage((it + 1) << 6, (it + 1) & 1);
        const unsigned short* La = ldsA[it & 1];
        const unsigned short* Lb = ldsB[it & 1];
        short8 aF[2][2], bF[2][2];
#pragma unroll
        for (int hh = 0; hh < 2; ++hh) {
            int kc = hh * 4 + quad;
#pragma unroll
            for (int mt = 0; mt < 2; ++mt)
                aF[hh][mt] = *(const short8*)&La[(wm * 32 + mt * 16 + ln) * 64 +
                                                ((kc ^ (ln & 7)) * 8)];
#pragma unroll
            for (int nt = 0; nt < 2; ++nt)
                bF[hh][nt] = *(const short8*)&Lb[(wn * 32 + nt * 16 + ln) * 64 +
                                                ((kc ^ (ln & 7)) * 8)];
        }
#pragma unroll
        for (int hh = 0; hh < 2; ++hh)
#pragma unroll
            for (int mt = 0; mt < 2; ++mt)
#pragma unroll
                for (int nt = 0; nt < 2; ++nt)
                    acc[mt][nt] = __builtin_amdgcn_mfma_f32_16x16x32_bf16(
                        aF[hh][mt], bF[hh][nt], acc[mt][nt], 0, 0, 0);
    }

    if (out_bf16) {
        unsigned short* C = (unsigned short*)Cout;
#pragma unroll
        for (int mt = 0; mt < 2; ++mt)
            for (int nt = 0; nt < 2; ++nt)
                for (int r = 0; r < 4; ++r) {
                    int rr = m0 + wm * 32 + mt * 16 + quad * 4 + r;
                    int cc = n0 + wn * 32 + nt * 16 + ln;
                    C[(size_t)rr * N + cc] = f2bf(acc[mt][nt][r]);
                }
        if (VtOut != nullptr && n0 == DM + HD) {   // V block: also write transposed
#pragma unroll
            for (int mt = 0; mt < 2; ++mt)
                for (int nt = 0; nt < 2; ++nt)
                    for (int r = 0; r < 4; ++r) {
                        int rr = m0 + wm * 32 + mt * 16 + quad * 4 + r;
                        int d = wn * 32 + nt * 16 + ln;          // 0..63
                        int bb = rr >> 11, s = rr & 2047;
                        VtOut[((size_t)bb * HD + d) * SEQ + s] = f2bf(acc[mt][nt][r]);
                    }
        }
    } else {
        float* C = (float*)Cout;
#pragma unroll
        for (int mt = 0; mt < 2; ++mt)
            for (int nt = 0; nt < 2; ++nt)
                for (int r = 0; r < 4; ++r) {
                    int rr = m0 + wm * 32 + mt * 16 + quad * 4 + r;
                    int cc = n0 + wn * 32 + nt * 16 + ln;
                    C[(size_t)rr * N + cc] = acc[mt][nt][r];
                }
    }
}

// ---------------- flash attention (multi-query, causal) ----------------
// R7 design (best measured: 51.9 us). 64-key steps: block stages K(64x64) +
// Vt(64x64) into double-buffered LDS via global_load_lds ((row&7) xor chunk
// swizzle). 4 waves share the tiles; wave w owns q-tile jg*4+w: jg mask-free
// steps + 1 partial step. pbuf (per-wave 16x64, xor-swizzled, no pad) for
// the P C-layout -> A-layout round trip; LDS total 40960 B = 4 blocks/CU.
// Constant-max streaming softmax; P stored by truncation (>>16).
__global__ __launch_bounds__(256) void attn_kernel(
        const unsigned short* __restrict__ QKV,
        const unsigned short* __restrict__ Vt,
        unsigned short* __restrict__ Y) {
    __shared__ unsigned short ldsK[2][64 * 64];
    __shared__ unsigned short ldsV[2][64 * 64];
    __shared__ unsigned short pbuf[4][16 * 64];   // swizzled, per-wave

    int lane = threadIdx.x & 63, wave = threadIdx.x >> 6;
    int ln = lane & 15, quad = lane >> 4;
    int bid = blockIdx.x;
    int jg = 31 - (bid >> 5);             // heavy-first
    int bh = bid & 31;
    int h = bh & 15, b = bh >> 4;
    int q0 = (jg * 4 + wave) * 16;
    const size_t baseRow = (size_t)b * SEQ;
    const unsigned short* Vb = Vt + (size_t)b * HD * SEQ;

    int t = threadIdx.x;
    int trow = t >> 3, tcb = t & 7;
    int cbg = tcb ^ (trow & 7);
    const unsigned short* gK = QKV + (baseRow + trow) * LDQ + DM + cbg * 8;
    const unsigned short* gV = Vb + (size_t)trow * SEQ + cbg * 8;
    int dstoff = trow * 64 + tcb * 8;

    auto stageKV = [&](int s0n, int buf) {
#pragma unroll
        for (int rr = 0; rr < 2; ++rr) {
            gload16(gK + (size_t)(s0n + 32 * rr) * LDQ, &ldsK[buf][dstoff + rr * 2048]);
            gload16(gV + (size_t)32 * rr * SEQ + s0n,   &ldsV[buf][dstoff + rr * 2048]);
        }
    };

    // Q fragments (A-layout)
    short8 aQ0, aQ1;
    {
        const unsigned short* qp = QKV + (baseRow + q0 + ln) * LDQ + h * HD + quad * 8;
        aQ0 = *(const short8*)(qp);
        aQ1 = *(const short8*)(qp + 32);
    }

    float lsum[4] = {0.f, 0.f, 0.f, 0.f};
    f32x4 o[4];
    for (int nt = 0; nt < 4; ++nt) o[nt] = f32x4{0, 0, 0, 0};

    const float c_exp = 0.1803368802f;    // 0.125 * log2(e)
    unsigned short* pb = &pbuf[wave][0];

    auto computeStep = [&](int s0, int buf, bool partial) {
        const unsigned short* Kb = ldsK[buf];
        const unsigned short* Vf = ldsV[buf];
#pragma unroll
        for (int c = 0; c < 4; ++c) {
            int kbase = s0 + c * 16;
            if (partial && kbase > q0 + 15) {   // fully masked tile: zero P
#pragma unroll
                for (int r = 0; r < 4; ++r) {
                    int row = quad * 4 + r;
                    pb[row * 64 + (((c * 2 + (ln >> 3)) ^ (row & 7)) * 8) + (ln & 7)] = 0;
                }
                continue;
            }
            short8 k0f = *(const short8*)&Kb[(c * 16 + ln) * 64 + ((quad ^ (ln & 7)) * 8)];
            short8 k1f = *(const short8*)&Kb[(c * 16 + ln) * 64 + (((4 + quad) ^ (ln & 7)) * 8)];
            f32x4 s = {0, 0, 0, 0};
            s = __builtin_amdgcn_mfma_f32_16x16x32_bf16(aQ0, k0f, s, 0, 0, 0);
            s = __builtin_amdgcn_mfma_f32_16x16x32_bf16(aQ1, k1f, s, 0, 0, 0);
            bool diag = partial && (kbase + 15 > q0);
#pragma unroll
            for (int r = 0; r < 4; ++r) {
                float e = __builtin_exp2f(s[r] * c_exp);
                if (diag && (kbase + ln > q0 + quad * 4 + r)) e = 0.f;  // causal
                lsum[r] += e;
                int row = quad * 4 + r;
                pb[row * 64 + (((c * 2 + (ln >> 3)) ^ (row & 7)) * 8) + (ln & 7)] =
                    (unsigned short)(__float_as_uint(e) >> 16);        // bf16 trunc
            }
        }
        short8 aP0 = *(const short8*)&pb[ln * 64 + ((quad ^ (ln & 7)) * 8)];
        short8 aP1 = *(const short8*)&pb[ln * 64 + (((4 + quad) ^ (ln & 7)) * 8)];
#pragma unroll
        for (int nt = 0; nt < 4; ++nt) {
            short8 v0 = *(const short8*)&Vf[(nt * 16 + ln) * 64 + ((quad ^ (ln & 7)) * 8)];
            short8 v1 = *(const short8*)&Vf[(nt * 16 + ln) * 64 + (((4 + quad) ^ (ln & 7)) * 8)];
            o[nt] = __builtin_amdgcn_mfma_f32_16x16x32_bf16(aP0, v0, o[nt], 0, 0, 0);
            o[nt] = __builtin_amdgcn_mfma_f32_16x16x32_bf16(aP1, v1, o[nt], 0, 0, 0);
        }
    };

    stageKV(0, 0);
    for (int it = 0; it < jg; ++it) {          // full steps, mask-free
        __syncthreads();
        stageKV((it + 1) * 64, (it + 1) & 1);
        computeStep(it * 64, it & 1, false);
    }
    __syncthreads();
    computeStep(jg * 64, jg & 1, true);        // the one partial step

    // epilogue: reduce l across the 16 lanes of each quad, then Y = O / l
    for (int off = 1; off < 16; off <<= 1)
#pragma unroll
        for (int r = 0; r < 4; ++r) lsum[r] += __shfl_xor(lsum[r], off);
#pragma unroll
    for (int r = 0; r < 4; ++r) {
        float inv = 1.0f / lsum[r];
        int t_idx = q0 + quad * 4 + r;
        unsigned short* yp = Y + (baseRow + t_idx) * DM + h * HD + ln;
        for (int nt = 0; nt < 4; ++nt)
            yp[nt * 16] = f2bf(o[nt][r] * inv);
    }
}

extern "C" void kernel_launch(void* const* d_in, const int* in_sizes, int n_in,
                              void* d_out, int out_size, void* d_ws, size_t ws_size,
                              hipStream_t stream) {
    const float* x  = (const float*)d_in[0];
    const float* Wq = (const float*)d_in[1];
    const float* Wk = (const float*)d_in[2];
    const float* Wv = (const float*)d_in[3];
    const float* Wo = (const float*)d_in[4];
    float* out = (float*)d_out;

    char* ws = (char*)d_ws;
    // workspace (22.8 MB): slot0 is xb until qkv-gemm completes, then y.
    unsigned short* xb  = (unsigned short*)(ws);                // 4096x1024 bf16 (8 MB)
    unsigned short* y   = (unsigned short*)(ws);                // alias: attn out
    unsigned short* wtq = (unsigned short*)(ws + 8388608);      // 1152x1024 bf16
    unsigned short* wot = (unsigned short*)(ws + 10747904);     // 1024x1024 bf16
    unsigned short* qkv = (unsigned short*)(ws + 12845056);     // 4096x1152 bf16
    unsigned short* Vt  = (unsigned short*)(ws + 22282240);     // 2x64x2048 bf16 (0.5 MB)

    const int BT = BATCH * SEQ;  // 4096 rows

    hipLaunchKernelGGL(cast_x_kernel, dim3(BT * DM / 4 / 256), dim3(256), 0, stream,
                       x, xb, BT * DM);
    hipLaunchKernelGGL(prep_w_kernel, dim3(DM / 32, DM / 32, 4), dim3(256), 0, stream,
                       Wq, Wk, Wv, Wo, wtq, wot);

    // QKV = x @ [Wq|Wk|Wv] -> bf16; V block also written transposed to Vt
    // 1152 blocks = 8 XCDs x 8 row-strips x 18 cols (XCD-aware remap inside)
    hipLaunchKernelGGL(gemm_bt_kernel, dim3((LDQ / 64) * (BT / 64)), dim3(256), 0, stream,
                       xb, wtq, (void*)qkv, Vt, BT, LDQ, DM, 1, LDQ / 64);

    // flash attention (64-key dbuf steps) -> y bf16 (overwrites xb, now dead)
    hipLaunchKernelGGL(attn_kernel, dim3(32 * 32), dim3(256), 0, stream,
                       qkv, Vt, y);

    // out = y @ Wo -> fp32; 1024 blocks = 8 XCDs x 8 row-strips x 16 cols
    hipLaunchKernelGGL(gemm_bt_kernel, dim3((DM / 64) * (BT / 64)), dim3(256), 0, stream,
                       y, wot, (void*)out, nullptr, BT, DM, DM, 0, DM / 64);
}